// Round 4
// baseline (2148.293 us; speedup 1.0000x reference)
//
#include <hip/hip_runtime.h>
#include <hip/hip_bf16.h>

typedef __attribute__((ext_vector_type(8))) short short8;
typedef __attribute__((ext_vector_type(4))) float floatx4;
typedef unsigned short u16;

#define DEVI __device__ __forceinline__

DEVI u16 f2bf(float f) {
  union { float f; unsigned u; } v; v.f = f;
  unsigned r = v.u + 0x7fffu + ((v.u >> 16) & 1u);   // round-to-nearest-even
  return (u16)(r >> 16);
}
DEVI float bf2f(u16 h) {
  union { unsigned u; float f; } v; v.u = (unsigned)h << 16; return v.f;
}

// st = silu(t_emb) -> bf16, 4096*256 elems = 262144 float4
__global__ __launch_bounds__(256) void silu_kernel(const float* __restrict__ t,
                                                   u16* __restrict__ out) {
  const int i = blockIdx.x * 256 + threadIdx.x;
  float4 v = ((const float4*)t)[i];
  ushort4 o;
  o.x = f2bf(v.x / (1.f + expf(-v.x)));
  o.y = f2bf(v.y / (1.f + expf(-v.y)));
  o.z = f2bf(v.z / (1.f + expf(-v.z)));
  o.w = f2bf(v.w / (1.f + expf(-v.w)));
  ((ushort4*)out)[i] = o;
}

// ---------------------------------------------------------------------------
// LayerNorm (+ optional adaLN modulation, bf16) over D=1024, one block per row.
// out_bf16 = ( (x-mean)*rstd*g + b ) * (1+s) + sh
// ---------------------------------------------------------------------------
template<bool MOD>
__global__ __launch_bounds__(256)
void ln_kernel(const float* __restrict__ h, const float* __restrict__ g,
               const float* __restrict__ b, const u16* __restrict__ s1,
               const u16* __restrict__ sh1, u16* __restrict__ out) {
  const int row = blockIdx.x;
  const int tid = threadIdx.x;
  const float4 xv = ((const float4*)(h + (size_t)row * 1024))[tid];
  float sm = xv.x + xv.y + xv.z + xv.w;
  float sq = xv.x * xv.x + xv.y * xv.y + xv.z * xv.z + xv.w * xv.w;
  #pragma unroll
  for (int off = 32; off > 0; off >>= 1) {
    sm += __shfl_down(sm, off);
    sq += __shfl_down(sq, off);
  }
  __shared__ float red[10];
  if ((tid & 63) == 0) { red[tid >> 6] = sm; red[4 + (tid >> 6)] = sq; }
  __syncthreads();
  if (tid == 0) {
    float S = red[0] + red[1] + red[2] + red[3];
    float Q = red[4] + red[5] + red[6] + red[7];
    float mean = S * (1.f / 1024.f);
    float var  = Q * (1.f / 1024.f) - mean * mean;
    red[8] = mean;
    red[9] = 1.f / sqrtf(var + 1e-5f);
  }
  __syncthreads();
  const float mean = red[8], rstd = red[9];
  const float4 gv = ((const float4*)g)[tid];
  const float4 bv = ((const float4*)b)[tid];
  float y0 = (xv.x - mean) * rstd * gv.x + bv.x;
  float y1 = (xv.y - mean) * rstd * gv.y + bv.y;
  float y2 = (xv.z - mean) * rstd * gv.z + bv.z;
  float y3 = (xv.w - mean) * rstd * gv.w + bv.w;
  if (MOD) {
    const ushort4 sv  = ((const ushort4*)(s1  + (size_t)row * 4096))[tid];
    const ushort4 shv = ((const ushort4*)(sh1 + (size_t)row * 4096))[tid];
    y0 = y0 * (1.f + bf2f(sv.x)) + bf2f(shv.x);
    y1 = y1 * (1.f + bf2f(sv.y)) + bf2f(shv.y);
    y2 = y2 * (1.f + bf2f(sv.z)) + bf2f(shv.z);
    y3 = y3 * (1.f + bf2f(sv.w)) + bf2f(shv.w);
  }
  ushort4 o;
  o.x = f2bf(y0); o.y = f2bf(y1); o.z = f2bf(y2); o.w = f2bf(y3);
  ((ushort4*)(out + (size_t)row * 1024))[tid] = o;
}

// ---------------------------------------------------------------------------
// NT GEMM with in-staging fp32->bf16 cast: C[M,N] = A[M,K] @ Bw[N,K]^T (+epi).
//   A: bf16 (AF32=false) or fp32 (AF32=true); Bw: always fp32 (raw weights).
// MODE 0: bf16 out, +bias
// MODE 1: f32 out, +bias (+addsrc[idx] if addsrc != nullptr)
// MODE 2: bf16 out, gelu_exact(acc+bias)
// Tile BMx128, BK=64, 4 waves (2x2). Reg-staged LDS with XOR swizzle on the
// WRITE side (slot = col ^ (row&7)); reads use the matching XOR. row&7==r&7
// on the read side because all row-base terms are multiples of 8.
// ---------------------------------------------------------------------------
template<int BM, int MODE, bool AF32>
__global__ __launch_bounds__(256, 2)
void gemm_kernel(const void* __restrict__ Av, const float* __restrict__ Bw,
                 const float* __restrict__ bias, const float* __restrict__ addsrc,
                 void* __restrict__ Cout, int M, int N, int K) {
  constexpr int BN = 128, BK = 64;
  constexpr int MI = BM / 32;   // 16-row frags per wave (m)
  constexpr int NI = 4;         // 16-col frags per wave (n)
  __shared__ u16 ldsA[BM * BK];
  __shared__ u16 ldsB[BN * BK];

  const int tid  = threadIdx.x;
  const int lane = tid & 63;
  const int wv   = tid >> 6;
  const int wr   = wv >> 1;
  const int wc   = wv & 1;
  const int r    = lane & 15;
  const int quad = lane >> 4;
  const int swz  = (r & 7) << 4;

  const int bm0 = blockIdx.y * BM;
  const int bn0 = blockIdx.x * BN;

  floatx4 acc[MI][NI] = {};

  for (int k0 = 0; k0 < K; k0 += BK) {
    // ---- stage A tile (BM x 64), 16B piece per (row, col) -------------
    #pragma unroll
    for (int p = tid; p < BM * 8; p += 256) {
      const int row = p >> 3;
      const int col = p & 7;
      short8 w;
      if constexpr (AF32) {
        const float* gp = (const float*)Av + (size_t)(bm0 + row) * K + k0 + col * 8;
        const float4 v0 = *(const float4*)gp;
        const float4 v1 = *(const float4*)(gp + 4);
        w[0] = (short)f2bf(v0.x); w[1] = (short)f2bf(v0.y);
        w[2] = (short)f2bf(v0.z); w[3] = (short)f2bf(v0.w);
        w[4] = (short)f2bf(v1.x); w[5] = (short)f2bf(v1.y);
        w[6] = (short)f2bf(v1.z); w[7] = (short)f2bf(v1.w);
      } else {
        const u16* gp = (const u16*)Av + (size_t)(bm0 + row) * K + k0 + col * 8;
        w = *(const short8*)gp;
      }
      *(short8*)((char*)ldsA + row * 128 + ((col ^ (row & 7)) << 4)) = w;
    }
    // ---- stage B tile (128 x 64), fp32 -> bf16 ------------------------
    #pragma unroll
    for (int p = tid; p < BN * 8; p += 256) {
      const int row = p >> 3;
      const int col = p & 7;
      const float* gp = Bw + (size_t)(bn0 + row) * K + k0 + col * 8;
      const float4 v0 = *(const float4*)gp;
      const float4 v1 = *(const float4*)(gp + 4);
      short8 w;
      w[0] = (short)f2bf(v0.x); w[1] = (short)f2bf(v0.y);
      w[2] = (short)f2bf(v0.z); w[3] = (short)f2bf(v0.w);
      w[4] = (short)f2bf(v1.x); w[5] = (short)f2bf(v1.y);
      w[6] = (short)f2bf(v1.z); w[7] = (short)f2bf(v1.w);
      *(short8*)((char*)ldsB + row * 128 + ((col ^ (row & 7)) << 4)) = w;
    }
    __syncthreads();
    // ---- MFMA over the two K=32 halves --------------------------------
    #pragma unroll
    for (int ks = 0; ks < 2; ++ks) {
      const int off = ((ks << 6) + (quad << 4)) ^ swz;
      short8 af[MI], bfr[NI];
      #pragma unroll
      for (int m = 0; m < MI; ++m) {
        const int row = wr * (BM / 2) + m * 16 + r;
        af[m] = *(const short8*)((const char*)ldsA + row * 128 + off);
      }
      #pragma unroll
      for (int n = 0; n < NI; ++n) {
        const int row = wc * 64 + n * 16 + r;
        bfr[n] = *(const short8*)((const char*)ldsB + row * 128 + off);
      }
      #pragma unroll
      for (int m = 0; m < MI; ++m)
        #pragma unroll
        for (int n = 0; n < NI; ++n)
          acc[m][n] = __builtin_amdgcn_mfma_f32_16x16x32_bf16(af[m], bfr[n],
                                                              acc[m][n], 0, 0, 0);
    }
    __syncthreads();
  }

  // Epilogue. C/D layout: col = lane&15, row = quad*4 + j  (m89-verified).
  const int colb  = bn0 + wc * 64;
  const int rowb0 = bm0 + wr * (BM / 2);
  #pragma unroll
  for (int n = 0; n < NI; ++n) {
    const int cn = colb + n * 16 + r;
    const float bv = bias[cn];
    #pragma unroll
    for (int m = 0; m < MI; ++m) {
      const int rowb = rowb0 + m * 16 + quad * 4;
      #pragma unroll
      for (int j = 0; j < 4; ++j) {
        const size_t idx = (size_t)(rowb + j) * N + cn;
        float val = acc[m][n][j] + bv;
        if constexpr (MODE == 0) {
          ((u16*)Cout)[idx] = f2bf(val);
        } else if constexpr (MODE == 1) {
          if (addsrc) val += addsrc[idx];
          ((float*)Cout)[idx] = val;
        } else {
          val = 0.5f * val * (1.f + erff(val * 0.70710678118654752f));
          ((u16*)Cout)[idx] = f2bf(val);
        }
      }
    }
  }
}

// ---------------------------------------------------------------------------
extern "C" void kernel_launch(void* const* d_in, const int* in_sizes, int n_in,
                              void* d_out, int out_size, void* d_ws, size_t ws_size,
                              hipStream_t stream) {
  (void)in_sizes; (void)n_in; (void)out_size; (void)ws_size;
  const float* x     = (const float*)d_in[0];
  const float* t_emb = (const float*)d_in[1];
  const float* cond  = (const float*)d_in[2];
  const float* in_w  = (const float*)d_in[3];
  const float* in_b  = (const float*)d_in[4];
  const float* ln1_g = (const float*)d_in[5];
  const float* ln1_b = (const float*)d_in[6];
  const float* wqkv  = (const float*)d_in[7];
  const float* bqkv  = (const float*)d_in[8];
  const float* wo    = (const float*)d_in[9];
  const float* bo    = (const float*)d_in[10];
  const float* ln2_g = (const float*)d_in[11];
  const float* ln2_b = (const float*)d_in[12];
  const float* w1    = (const float*)d_in[13];
  const float* b1    = (const float*)d_in[14];
  const float* w2    = (const float*)d_in[15];
  const float* b2    = (const float*)d_in[16];
  const float* ada_w = (const float*)d_in[17];
  const float* ada_b = (const float*)d_in[18];
  const float* oln_g = (const float*)d_in[19];
  const float* oln_b = (const float*)d_in[20];
  const float* out_w = (const float*)d_in[21];
  const float* out_b = (const float*)d_in[22];
  float* out = (float*)d_out;

  // --- workspace layout (~66 MB) -----------------------------------------
  // ada is bf16 [4096,4096] (32 MB); a1 (bf16, 32 MB) overlays it — ada[l]
  // is fully consumed by the two ln_kernel calls before a1[l] is written.
  char* p = (char*)d_ws;
  auto alloc = [&](size_t n) { char* r = p; p += (n + 255) & ~(size_t)255; return r; };
  u16*   stb = (u16*)  alloc((size_t)4096 * 256  * 2);   //  2 MB
  float* h   = (float*)alloc((size_t)4096 * 1024 * 4);   // 16 MB
  u16*   ada = (u16*)  alloc((size_t)4096 * 4096 * 2);   // 32 MB (bf16)
  u16*   a1  = ada;                                      // overlay
  u16*   xn  = (u16*)  alloc((size_t)4096 * 1024 * 2);   //  8 MB
  u16*   vb  = (u16*)  alloc((size_t)4096 * 1024 * 2);   //  8 MB

  silu_kernel<<<1024, 256, 0, stream>>>(t_emb, stb);

  // h = x @ in_w^T + in_b + condition           (A = x, fp32)
  gemm_kernel<64, 1, true><<<dim3(8, 64), 256, 0, stream>>>(
      x, in_w, in_b, cond, h, 4096, 1024, 1024);

  for (int l = 0; l < 4; ++l) {
    // ada = st @ ada_w^T + ada_b   [B, 4096] bf16
    gemm_kernel<128, 0, false><<<dim3(32, 32), 256, 0, stream>>>(
        stb, ada_w + (size_t)l * 1048576, ada_b + l * 4096, nullptr, ada,
        4096, 4096, 256);
    // xn = LN1(h)*(1+s1)+sh1
    ln_kernel<true><<<4096, 256, 0, stream>>>(h, ln1_g + l * 1024, ln1_b + l * 1024,
                                              ada, ada + 1024, xn);
    // v = xn @ wv^T + bv   (seq_len==1 => attn==1 exactly; q,k are dead)
    gemm_kernel<64, 0, false><<<dim3(8, 64), 256, 0, stream>>>(
        xn, wqkv + (size_t)l * 3145728 + 2097152, bqkv + l * 3072 + 2048,
        nullptr, vb, 4096, 1024, 1024);
    // h += v @ wo^T + bo
    gemm_kernel<64, 1, false><<<dim3(8, 64), 256, 0, stream>>>(
        vb, wo + (size_t)l * 1048576, bo + l * 1024, h, h, 4096, 1024, 1024);
    // xn = LN2(h)*(1+s2)+sh2
    ln_kernel<true><<<4096, 256, 0, stream>>>(h, ln2_g + l * 1024, ln2_b + l * 1024,
                                              ada + 2048, ada + 3072, xn);
    // a1 = gelu_exact(xn @ w1^T + b1)   (a1 overlays ada)
    gemm_kernel<128, 2, false><<<dim3(32, 32), 256, 0, stream>>>(
        xn, w1 + (size_t)l * 4194304, b1 + l * 4096, nullptr, a1,
        4096, 4096, 1024);
    // h += a1 @ w2^T + b2
    gemm_kernel<64, 1, false><<<dim3(8, 64), 256, 0, stream>>>(
        a1, w2 + (size_t)l * 4194304, b2 + l * 1024, h, h, 4096, 1024, 4096);
  }
  // out = LN(h) @ out_w^T + out_b
  ln_kernel<false><<<4096, 256, 0, stream>>>(h, oln_g, oln_b, nullptr, nullptr, xn);
  gemm_kernel<64, 1, false><<<dim3(8, 64), 256, 0, stream>>>(
      xn, out_w, out_b, nullptr, out, 4096, 1024, 1024);
}

// Round 5
// 1390.909 us; speedup vs baseline: 1.5445x; 1.5445x over previous
//
#include <hip/hip_runtime.h>
#include <hip/hip_bf16.h>

typedef __attribute__((ext_vector_type(8))) short short8;
typedef __attribute__((ext_vector_type(4))) float floatx4;
typedef unsigned short u16;

#define DEVI __device__ __forceinline__

DEVI u16 f2bf(float f) {
  union { float f; unsigned u; } v; v.f = f;
  unsigned r = v.u + 0x7fffu + ((v.u >> 16) & 1u);   // round-to-nearest-even
  return (u16)(r >> 16);
}
DEVI float bf2f(u16 h) {
  union { unsigned u; float f; } v; v.u = (unsigned)h << 16; return v.f;
}

// st = silu(t_emb) -> bf16, 4096*256 elems = 262144 float4
__global__ __launch_bounds__(256) void silu_kernel(const float* __restrict__ t,
                                                   u16* __restrict__ out) {
  const int i = blockIdx.x * 256 + threadIdx.x;
  float4 v = ((const float4*)t)[i];
  ushort4 o;
  o.x = f2bf(v.x / (1.f + expf(-v.x)));
  o.y = f2bf(v.y / (1.f + expf(-v.y)));
  o.z = f2bf(v.z / (1.f + expf(-v.z)));
  o.w = f2bf(v.w / (1.f + expf(-v.w)));
  ((ushort4*)out)[i] = o;
}

// ---------------------------------------------------------------------------
// LayerNorm (+ optional adaLN modulation, bf16) over D=1024, one block per row.
// ---------------------------------------------------------------------------
template<bool MOD>
__global__ __launch_bounds__(256)
void ln_kernel(const float* __restrict__ h, const float* __restrict__ g,
               const float* __restrict__ b, const u16* __restrict__ s1,
               const u16* __restrict__ sh1, u16* __restrict__ out) {
  const int row = blockIdx.x;
  const int tid = threadIdx.x;
  const float4 xv = ((const float4*)(h + (size_t)row * 1024))[tid];
  float sm = xv.x + xv.y + xv.z + xv.w;
  float sq = xv.x * xv.x + xv.y * xv.y + xv.z * xv.z + xv.w * xv.w;
  #pragma unroll
  for (int off = 32; off > 0; off >>= 1) {
    sm += __shfl_down(sm, off);
    sq += __shfl_down(sq, off);
  }
  __shared__ float red[10];
  if ((tid & 63) == 0) { red[tid >> 6] = sm; red[4 + (tid >> 6)] = sq; }
  __syncthreads();
  if (tid == 0) {
    float S = red[0] + red[1] + red[2] + red[3];
    float Q = red[4] + red[5] + red[6] + red[7];
    float mean = S * (1.f / 1024.f);
    float var  = Q * (1.f / 1024.f) - mean * mean;
    red[8] = mean;
    red[9] = 1.f / sqrtf(var + 1e-5f);
  }
  __syncthreads();
  const float mean = red[8], rstd = red[9];
  const float4 gv = ((const float4*)g)[tid];
  const float4 bv = ((const float4*)b)[tid];
  float y0 = (xv.x - mean) * rstd * gv.x + bv.x;
  float y1 = (xv.y - mean) * rstd * gv.y + bv.y;
  float y2 = (xv.z - mean) * rstd * gv.z + bv.z;
  float y3 = (xv.w - mean) * rstd * gv.w + bv.w;
  if (MOD) {
    const ushort4 sv  = ((const ushort4*)(s1  + (size_t)row * 4096))[tid];
    const ushort4 shv = ((const ushort4*)(sh1 + (size_t)row * 4096))[tid];
    y0 = y0 * (1.f + bf2f(sv.x)) + bf2f(shv.x);
    y1 = y1 * (1.f + bf2f(sv.y)) + bf2f(shv.y);
    y2 = y2 * (1.f + bf2f(sv.z)) + bf2f(shv.z);
    y3 = y3 * (1.f + bf2f(sv.w)) + bf2f(shv.w);
  }
  ushort4 o;
  o.x = f2bf(y0); o.y = f2bf(y1); o.z = f2bf(y2); o.w = f2bf(y3);
  ((ushort4*)(out + (size_t)row * 1024))[tid] = o;
}

// ---------------------------------------------------------------------------
// NT GEMM, depth-1 prefetched reg-staging: C[M,N] = A[M,K] @ Bw[N,K]^T (+epi).
//   A: bf16 (AF32=false) or fp32 (AF32=true); Bw: always fp32 (raw weights).
// MODE 0: bf16 out, +bias | MODE 1: f32 out, +bias (+addsrc) | MODE 2: gelu.
// K-loop: ds_write(regs[t]) -> barrier -> issue loads[t+1] -> MFMA(t) -> barrier.
// Loads for t+1 stay in flight across the MFMA phase (T3-minimal pipeline);
// the vmcnt drain lands at the next ds_write, not on the critical path.
// LDS XOR-swizzle on write side (slot = col ^ (row&7)); matching read XOR.
// ---------------------------------------------------------------------------
template<int BM, int MODE, bool AF32>
__global__ __launch_bounds__(256, 2)
void gemm_kernel(const void* __restrict__ Av, const float* __restrict__ Bw,
                 const float* __restrict__ bias, const float* __restrict__ addsrc,
                 void* __restrict__ Cout, int M, int N, int K) {
  constexpr int BN = 128, BK = 64;
  constexpr int MI = BM / 32;        // 16-row frags per wave (m)
  constexpr int NI = 4;              // 16-col frags per wave (n)
  constexpr int NA = BM * 8 / 256;   // A staging pieces per thread (2 or 4)
  constexpr int NB = BN * 8 / 256;   // B staging pieces per thread (4)
  __shared__ u16 ldsA[BM * BK];
  __shared__ u16 ldsB[BN * BK];

  const int tid  = threadIdx.x;
  const int lane = tid & 63;
  const int wv   = tid >> 6;
  const int wr   = wv >> 1;
  const int wc   = wv & 1;
  const int r    = lane & 15;
  const int quad = lane >> 4;
  const int swz  = (r & 7) << 4;

  const int bm0 = blockIdx.y * BM;
  const int bn0 = blockIdx.x * BN;

  const int srow = tid >> 3;   // 0..31, staging row within 32-row stripe
  const int scol = tid & 7;    // 16B piece within the 64-elem row

  floatx4 acc[MI][NI] = {};

  // staging registers (one tile in flight)
  float4 af0[NA], af1[NA];     // AF32 path
  short8 ab[NA];               // bf16 path
  float4 bf0[NB], bf1[NB];

  auto load_tile = [&](int k0) {
    #pragma unroll
    for (int i = 0; i < NA; ++i) {
      const int row = srow + 32 * i;
      if constexpr (AF32) {
        const float* gp = (const float*)Av + (size_t)(bm0 + row) * K + k0 + scol * 8;
        af0[i] = *(const float4*)gp;
        af1[i] = *(const float4*)(gp + 4);
      } else {
        const u16* gp = (const u16*)Av + (size_t)(bm0 + row) * K + k0 + scol * 8;
        ab[i] = *(const short8*)gp;
      }
    }
    #pragma unroll
    for (int i = 0; i < NB; ++i) {
      const int row = srow + 32 * i;
      const float* gp = Bw + (size_t)(bn0 + row) * K + k0 + scol * 8;
      bf0[i] = *(const float4*)gp;
      bf1[i] = *(const float4*)(gp + 4);
    }
  };

  auto write_lds = [&]() {
    #pragma unroll
    for (int i = 0; i < NA; ++i) {
      const int row = srow + 32 * i;
      short8 w;
      if constexpr (AF32) {
        w[0] = (short)f2bf(af0[i].x); w[1] = (short)f2bf(af0[i].y);
        w[2] = (short)f2bf(af0[i].z); w[3] = (short)f2bf(af0[i].w);
        w[4] = (short)f2bf(af1[i].x); w[5] = (short)f2bf(af1[i].y);
        w[6] = (short)f2bf(af1[i].z); w[7] = (short)f2bf(af1[i].w);
      } else {
        w = ab[i];
      }
      *(short8*)((char*)ldsA + row * 128 + ((scol ^ (row & 7)) << 4)) = w;
    }
    #pragma unroll
    for (int i = 0; i < NB; ++i) {
      const int row = srow + 32 * i;
      short8 w;
      w[0] = (short)f2bf(bf0[i].x); w[1] = (short)f2bf(bf0[i].y);
      w[2] = (short)f2bf(bf0[i].z); w[3] = (short)f2bf(bf0[i].w);
      w[4] = (short)f2bf(bf1[i].x); w[5] = (short)f2bf(bf1[i].y);
      w[6] = (short)f2bf(bf1[i].z); w[7] = (short)f2bf(bf1[i].w);
      *(short8*)((char*)ldsB + row * 128 + ((scol ^ (row & 7)) << 4)) = w;
    }
  };

  const int nt = K / BK;
  load_tile(0);                            // prologue
  for (int t = 0; t < nt; ++t) {
    write_lds();                           // vmcnt drain happens here
    __syncthreads();
    if (t + 1 < nt) load_tile((t + 1) * BK);   // in flight across MFMA
    #pragma unroll
    for (int ks = 0; ks < 2; ++ks) {
      const int off = ((ks << 6) + (quad << 4)) ^ swz;
      short8 afr[MI], bfr[NI];
      #pragma unroll
      for (int m = 0; m < MI; ++m) {
        const int row = wr * (BM / 2) + m * 16 + r;
        afr[m] = *(const short8*)((const char*)ldsA + row * 128 + off);
      }
      #pragma unroll
      for (int n = 0; n < NI; ++n) {
        const int row = wc * 64 + n * 16 + r;
        bfr[n] = *(const short8*)((const char*)ldsB + row * 128 + off);
      }
      #pragma unroll
      for (int m = 0; m < MI; ++m)
        #pragma unroll
        for (int n = 0; n < NI; ++n)
          acc[m][n] = __builtin_amdgcn_mfma_f32_16x16x32_bf16(afr[m], bfr[n],
                                                              acc[m][n], 0, 0, 0);
    }
    __syncthreads();
  }

  // Epilogue. C/D layout: col = lane&15, row = quad*4 + j  (m89-verified).
  const int colb  = bn0 + wc * 64;
  const int rowb0 = bm0 + wr * (BM / 2);
  #pragma unroll
  for (int n = 0; n < NI; ++n) {
    const int cn = colb + n * 16 + r;
    const float bv = bias[cn];
    #pragma unroll
    for (int m = 0; m < MI; ++m) {
      const int rowb = rowb0 + m * 16 + quad * 4;
      #pragma unroll
      for (int j = 0; j < 4; ++j) {
        const size_t idx = (size_t)(rowb + j) * N + cn;
        float val = acc[m][n][j] + bv;
        if constexpr (MODE == 0) {
          ((u16*)Cout)[idx] = f2bf(val);
        } else if constexpr (MODE == 1) {
          if (addsrc) val += addsrc[idx];
          ((float*)Cout)[idx] = val;
        } else {
          val = 0.5f * val * (1.f + erff(val * 0.70710678118654752f));
          ((u16*)Cout)[idx] = f2bf(val);
        }
      }
    }
  }
}

// ---------------------------------------------------------------------------
extern "C" void kernel_launch(void* const* d_in, const int* in_sizes, int n_in,
                              void* d_out, int out_size, void* d_ws, size_t ws_size,
                              hipStream_t stream) {
  (void)in_sizes; (void)n_in; (void)out_size; (void)ws_size;
  const float* x     = (const float*)d_in[0];
  const float* t_emb = (const float*)d_in[1];
  const float* cond  = (const float*)d_in[2];
  const float* in_w  = (const float*)d_in[3];
  const float* in_b  = (const float*)d_in[4];
  const float* ln1_g = (const float*)d_in[5];
  const float* ln1_b = (const float*)d_in[6];
  const float* wqkv  = (const float*)d_in[7];
  const float* bqkv  = (const float*)d_in[8];
  const float* wo    = (const float*)d_in[9];
  const float* bo    = (const float*)d_in[10];
  const float* ln2_g = (const float*)d_in[11];
  const float* ln2_b = (const float*)d_in[12];
  const float* w1    = (const float*)d_in[13];
  const float* b1    = (const float*)d_in[14];
  const float* w2    = (const float*)d_in[15];
  const float* b2    = (const float*)d_in[16];
  const float* ada_w = (const float*)d_in[17];
  const float* ada_b = (const float*)d_in[18];
  const float* oln_g = (const float*)d_in[19];
  const float* oln_b = (const float*)d_in[20];
  const float* out_w = (const float*)d_in[21];
  const float* out_b = (const float*)d_in[22];
  float* out = (float*)d_out;

  // --- workspace layout (~66 MB), unchanged from R4 (passed) -------------
  char* p = (char*)d_ws;
  auto alloc = [&](size_t n) { char* r = p; p += (n + 255) & ~(size_t)255; return r; };
  u16*   stb = (u16*)  alloc((size_t)4096 * 256  * 2);   //  2 MB
  float* h   = (float*)alloc((size_t)4096 * 1024 * 4);   // 16 MB
  u16*   ada = (u16*)  alloc((size_t)4096 * 4096 * 2);   // 32 MB (bf16)
  u16*   a1  = ada;                                      // overlay
  u16*   xn  = (u16*)  alloc((size_t)4096 * 1024 * 2);   //  8 MB
  u16*   vb  = (u16*)  alloc((size_t)4096 * 1024 * 2);   //  8 MB

  silu_kernel<<<1024, 256, 0, stream>>>(t_emb, stb);

  // h = x @ in_w^T + in_b + condition           (A = x, fp32)
  gemm_kernel<64, 1, true><<<dim3(8, 64), 256, 0, stream>>>(
      x, in_w, in_b, cond, h, 4096, 1024, 1024);

  for (int l = 0; l < 4; ++l) {
    // ada = st @ ada_w^T + ada_b   [B, 4096] bf16
    gemm_kernel<128, 0, false><<<dim3(32, 32), 256, 0, stream>>>(
        stb, ada_w + (size_t)l * 1048576, ada_b + l * 4096, nullptr, ada,
        4096, 4096, 256);
    // xn = LN1(h)*(1+s1)+sh1
    ln_kernel<true><<<4096, 256, 0, stream>>>(h, ln1_g + l * 1024, ln1_b + l * 1024,
                                              ada, ada + 1024, xn);
    // v = xn @ wv^T + bv   (seq_len==1 => attn==1 exactly; q,k are dead)
    gemm_kernel<64, 0, false><<<dim3(8, 64), 256, 0, stream>>>(
        xn, wqkv + (size_t)l * 3145728 + 2097152, bqkv + l * 3072 + 2048,
        nullptr, vb, 4096, 1024, 1024);
    // h += v @ wo^T + bo
    gemm_kernel<64, 1, false><<<dim3(8, 64), 256, 0, stream>>>(
        vb, wo + (size_t)l * 1048576, bo + l * 1024, h, h, 4096, 1024, 1024);
    // xn = LN2(h)*(1+s2)+sh2
    ln_kernel<true><<<4096, 256, 0, stream>>>(h, ln2_g + l * 1024, ln2_b + l * 1024,
                                              ada + 2048, ada + 3072, xn);
    // a1 = gelu_exact(xn @ w1^T + b1)   (a1 overlays ada)
    gemm_kernel<128, 2, false><<<dim3(32, 32), 256, 0, stream>>>(
        xn, w1 + (size_t)l * 4194304, b1 + l * 4096, nullptr, a1,
        4096, 4096, 1024);
    // h += a1 @ w2^T + b2
    gemm_kernel<64, 1, false><<<dim3(8, 64), 256, 0, stream>>>(
        a1, w2 + (size_t)l * 4194304, b2 + l * 1024, h, h, 4096, 1024, 4096);
  }
  // out = LN(h) @ out_w^T + out_b
  ln_kernel<false><<<4096, 256, 0, stream>>>(h, oln_g, oln_b, nullptr, nullptr, xn);
  gemm_kernel<64, 1, false><<<dim3(8, 64), 256, 0, stream>>>(
      xn, out_w, out_b, nullptr, out, 4096, 1024, 1024);
}